// Round 2
// baseline (218.705 us; speedup 1.0000x reference)
//
#include <hip/hip_runtime.h>
#include <math.h>

#define B_ 4
#define N_ 2048
#define C_ 768
#define H_ 12
#define D_ 64
// softmax exp(s/8) computed as exp2(s * 0.125*log2(e)); folded into Q pre-scale
#define QKSCALE_ 0.18033688011112042f

typedef unsigned short u16;
typedef unsigned int u32;
typedef short s16x8 __attribute__((ext_vector_type(8)));
typedef float f32x4 __attribute__((ext_vector_type(4)));
typedef float f32x16 __attribute__((ext_vector_type(16)));

__device__ __forceinline__ u16 f2bf(float f) {
    union { float f; u32 u; } v; v.f = f;
    u32 r = (v.u + 0x7fffu + ((v.u >> 16) & 1u)) >> 16;
    return (u16)r;
}

// async global->LDS, 16B per lane; LDS dest = wave-uniform base + lane*16
__device__ __forceinline__ void gl_lds16(const u16* g, u16* l) {
    __builtin_amdgcn_global_load_lds(
        (__attribute__((address_space(1))) void*)g,
        (__attribute__((address_space(3))) void*)l, 16, 0, 0);
}

// fused fp32 -> bf16 conversion of x, w_qkv, w_proj in one launch
#define NX4_  (B_ * N_ * C_ / 4)
#define NWQ4_ (3 * C_ * C_ / 4)
#define NWP4_ (C_ * C_ / 4)
__global__ __launch_bounds__(256) void cvt_all(const float4* __restrict__ x,
                                               const float4* __restrict__ wq,
                                               const float4* __restrict__ wp,
                                               ushort4* __restrict__ xb,
                                               ushort4* __restrict__ wqb,
                                               ushort4* __restrict__ wpb)
{
    const int tot = NX4_ + NWQ4_ + NWP4_;
    int i = blockIdx.x * blockDim.x + threadIdx.x;
    const int stride = gridDim.x * blockDim.x;
    for (; i < tot; i += stride) {
        const float4* s; ushort4* d; int j;
        if (i < NX4_)              { s = x;  d = xb;  j = i; }
        else if (i < NX4_ + NWQ4_) { s = wq; d = wqb; j = i - NX4_; }
        else                       { s = wp; d = wpb; j = i - NX4_ - NWQ4_; }
        float4 v = s[j];
        ushort4 o;
        o.x = f2bf(v.x); o.y = f2bf(v.y); o.z = f2bf(v.z); o.w = f2bf(v.w);
        d[j] = o;
    }
}

// C(M,N) = A(M,K) * B(N,K)^T [+bias]. BMx128 tile, BK=64 (2 MFMA K-steps per
// barrier), double-buffered global_load_lds staging.
// LDS rows of 64 u16 (128B) with 16B-chunk XOR swizzle chunk' = chunk^(row&7).
template<int BM, int WPEU, bool OUT_BF16, bool BIAS, bool QSCALE>
__global__ __launch_bounds__(256, WPEU) void gemm_mfma(const u16* __restrict__ A,
                                                       const u16* __restrict__ Bm,
                                                       const float* __restrict__ bias,
                                                       void* __restrict__ Cout,
                                                       int M, int N, int K)
{
    constexpr int MF  = BM / 32;           // m-frags per wave
    constexpr int AC  = BM / 32;           // A gl_lds calls per wave (8 rows each)
    constexpr int ASZ = BM * 64, BSZ = 128 * 64;
    __shared__ __align__(16) u16 As[2 * ASZ];
    __shared__ __align__(16) u16 Bs[2 * BSZ];
    const int tid  = threadIdx.x;
    const int wv   = tid >> 6;
    const int lane = tid & 63;
    const int lr   = lane & 15;
    const int lq   = lane >> 4;
    const int wm   = (wv >> 1) * (BM / 2);
    const int wn   = (wv & 1) * 64;
    const int row0 = blockIdx.y * BM, col0 = blockIdx.x * 128;

    f32x4 acc[MF][4];
    #pragma unroll
    for (int i = 0; i < MF; i++)
        #pragma unroll
        for (int j = 0; j < 4; j++) { f32x4 z = {0.f,0.f,0.f,0.f}; acc[i][j] = z; }

    const int srow   = lane >> 3;                    // 0..7
    const int schunk = ((lane & 7) ^ srow) * 8;      // swizzled global chunk (u16)

    const int arow_base = (BM / 4) * wv;             // wave's A rows
    const u16* gA = A + (size_t)(row0 + arow_base + srow) * K + schunk;
    const u16* gB = Bm + (size_t)(col0 + 32 * wv + srow) * K + schunk;
    const int aoff = arow_base * 64;
    const int boff = (32 * wv) * 64;

    const int nIter = K / 64;

    // prologue: issue tile 0 into buffer 0
    #pragma unroll
    for (int c = 0; c < AC; c++)
        gl_lds16(gA + (size_t)(8 * c) * K, As + aoff + c * 8 * 64);
    #pragma unroll
    for (int c = 0; c < 4; c++)
        gl_lds16(gB + (size_t)(8 * c) * K, Bs + boff + c * 8 * 64);

    for (int t = 0; t < nIter; t++) {
        const int cur = t & 1;
        __syncthreads();   // buf[cur] staged; buf[cur^1] free
        if (t + 1 < nIter) {
            const int k1 = (t + 1) * 64;
            const int nb = cur ^ 1;
            #pragma unroll
            for (int c = 0; c < AC; c++)
                gl_lds16(gA + (size_t)(8 * c) * K + k1, As + nb * ASZ + aoff + c * 8 * 64);
            #pragma unroll
            for (int c = 0; c < 4; c++)
                gl_lds16(gB + (size_t)(8 * c) * K + k1, Bs + nb * BSZ + boff + c * 8 * 64);
        }
        const u16* __restrict__ Ac = As + cur * ASZ;
        const u16* __restrict__ Bc = Bs + cur * BSZ;
        #pragma unroll
        for (int kk = 0; kk < 2; kk++) {
            const int fo = ((4 * kk + lq) ^ (lr & 7)) * 8;   // swizzled frag pos
            s16x8 af[MF], bfr[4];
            #pragma unroll
            for (int i = 0; i < MF; i++)
                af[i] = *(const s16x8*)&Ac[(wm + 16*i + lr) * 64 + fo];
            #pragma unroll
            for (int j = 0; j < 4; j++)
                bfr[j] = *(const s16x8*)&Bc[(wn + 16*j + lr) * 64 + fo];
            #pragma unroll
            for (int i = 0; i < MF; i++)
                #pragma unroll
                for (int j = 0; j < 4; j++)
                    acc[i][j] = __builtin_amdgcn_mfma_f32_16x16x32_bf16(af[i], bfr[j], acc[i][j], 0, 0, 0);
        }
    }

    #pragma unroll
    for (int i = 0; i < MF; i++) {
        #pragma unroll
        for (int j = 0; j < 4; j++) {
            const int col = col0 + wn + 16*j + lr;
            float bv = BIAS ? bias[col] : 0.f;
            #pragma unroll
            for (int r = 0; r < 4; r++) {
                const int row = row0 + wm + 16*i + lq*4 + r;
                float v = acc[i][j][r] + bv;
                if (QSCALE && col < C_) v *= QKSCALE_;
                if (OUT_BF16) ((u16*)Cout)[(size_t)row * N + col] = f2bf(v);
                else          ((float*)Cout)[(size_t)row * N + col] = v;
            }
        }
    }
}

// MFMA flash attention, 32x32x16 MFMAs, fully in-register softmax (T12).
// R2 changes vs R1:
//  * K staging is now direct global_load_lds (async DMA): LDS dest is linear
//    (wave base + lane*16B), and the XOR chunk-swizzle is applied to the
//    per-lane GLOBAL source address instead (G21/m173 both-sides pattern) —
//    LDS contents are bit-identical to R1, the read side is unchanged. This
//    deletes the whole K register round-trip (2 global b128 loads + 2
//    ds_write_b128 per thread-tile + 8 VGPRs of kr pipeline).
//  * XCD-aware block swizzle: all 16 q-tiles of one (b,h) get wgids congruent
//    mod 8 -> same XCD -> its K/V (512KB) is fetched into that XCD's L2 once
//    instead of 8x. 6 heads/XCD * 512KB = 3MB fits the 4MB L2.
//  * T5 s_setprio(1) around the QK^T and PV MFMA clusters.
// V keeps the register-staged transpose-pack path (tr_read needs the 8x[32][16]
// layout to be conflict-free per m217 — not attempted).
__global__ __launch_bounds__(256, 3) void attn_mfma(const u16* __restrict__ qkv,
                                                    u16* __restrict__ attout)
{
    __shared__ __align__(16) u16 Ks[2][64 * 64];   // [key][16B-chunk ^ (key&7)]
    __shared__ __align__(16) u16 Vt[2][64][72];    // [d][key], 8-key chunks rotated by d>>3

    const int tid  = threadIdx.x;
    const int wv   = tid >> 6;
    const int lane = tid & 63;
    const int l31  = lane & 31;
    const int hi   = lane >> 5;

    // XCD swizzle: wgid%8 = XCD (round-robin dispatch); give each XCD 6 whole
    // (b,h) groups so K/V is L2-resident per-XCD.
    const int wgid = blockIdx.y * gridDim.x + blockIdx.x;   // 0..767
    const int ix   = wgid >> 3;                             // 0..95 within XCD
    const int bh   = (wgid & 7) * 6 + (ix >> 4);            // 6 bh per XCD
    const int n0   = (ix & 15) * 128;                       // q-tile
    const int b = bh / H_, h = bh % H_;
    const size_t rs = 3 * C_;

    const u16* Qg = qkv + ((size_t)b * N_ + n0) * rs + h * D_;
    const u16* Kg = qkv + ((size_t)b * N_) * rs + C_ + h * D_;
    const u16* Vg = Kg + C_;

    // Q B-frags (32x32x16): lane holds qrow = l31, d = 16*kk + 8*hi + e
    s16x8 qf[4];
    #pragma unroll
    for (int kk = 0; kk < 4; kk++)
        qf[kk] = *(const s16x8*)(Qg + (size_t)(32*wv + l31) * rs + kk*16 + hi*8);

    const f32x16 z16 = {0.f,0.f,0.f,0.f,0.f,0.f,0.f,0.f,
                        0.f,0.f,0.f,0.f,0.f,0.f,0.f,0.f};
    f32x16 oacc[2] = {z16, z16};   // j2: d-blocks 32*j2 + l31
    float li = 0.f;

    // ---- K staging via global_load_lds (2 calls/wave, 8 keys each) ----
    // lane l covers key (l>>3), LDS slot (l&7); slot s of key k must hold
    // global chunk s^(k&7), and (16wv+8q+(l>>3))&7 == (l>>3)&7, so the
    // per-lane source chunk is ((l&7)^(l>>3&7)) for both calls.
    const int kkey = lane >> 3;                              // 0..7
    const u16* Kg_l = Kg + (size_t)(16*wv + kkey) * rs + ((lane & 7) ^ kkey) * 8;

    // ---- V staging (register transpose-pack, unchanged) ----
    const int vc = tid & 7, vp = tid >> 3;           // V: 2 keys, 8 d
    const int vkey0 = 2 * vp, vd0 = vc * 8;
    const int vcol0 = (vkey0 + 8 * vc) & 63;

    // prologue: K tile 0 -> DMA into buf0; V tile 0 -> regs -> buf0; V tile 1 -> regs
    gl_lds16(Kg_l,                    &Ks[0][(16*wv) * 64]);
    gl_lds16(Kg_l + (size_t)8 * rs,   &Ks[0][(16*wv + 8) * 64]);

    s16x8 vr0, vr1;
    {
        const u16* vp2 = Vg + (size_t)vkey0 * rs + vd0;
        vr0 = *(const s16x8*)vp2; vr1 = *(const s16x8*)(vp2 + rs);
    }
    #pragma unroll
    for (int u = 0; u < 8; u++) {
        u32 pk = (u32)(u16)vr0[u] | ((u32)(u16)vr1[u] << 16);
        *(u32*)&Vt[0][vd0 + u][vcol0] = pk;
    }
    {
        const u16* vp2 = Vg + (size_t)(64 + vkey0) * rs + vd0;
        vr0 = *(const s16x8*)vp2; vr1 = *(const s16x8*)(vp2 + rs);
    }

    const int NT = N_ / 64;
    for (int t = 0; t < NT; t++) {
        const int cur = t & 1, nxt = cur ^ 1;
        __syncthreads();   // buf[cur] staged (DMA drained); buf[nxt] readers done
        if (t + 1 < NT) {
            // issue next K tile DMA first — full tile of latency to land
            const size_t ko = (size_t)(t + 1) * 64 * rs;
            gl_lds16(Kg_l + ko,                  &Ks[nxt][(16*wv) * 64]);
            gl_lds16(Kg_l + ko + (size_t)8 * rs, &Ks[nxt][(16*wv + 8) * 64]);
            // store reg-prefetched V tile t+1
            #pragma unroll
            for (int u = 0; u < 8; u++) {
                u32 pk = (u32)(u16)vr0[u] | ((u32)(u16)vr1[u] << 16);
                *(u32*)&Vt[nxt][vd0 + u][vcol0] = pk;
            }
        }
        if (t + 2 < NT) {
            const u16* vp2 = Vg + (size_t)((t+2)*64 + vkey0) * rs + vd0;
            vr0 = *(const s16x8*)vp2; vr1 = *(const s16x8*)(vp2 + rs);
        }

        // S^T = K Q^T : two 32-key blocks (j), k = d in 4 chunks of 16 (kk)
        #define KF(j, kk) (*(const s16x8*)&Ks[cur][(32*(j) + l31) * 64 + \
                           ((2*(kk) + hi) ^ (l31 & 7)) * 8])
        __builtin_amdgcn_s_setprio(1);
        f32x16 st0 = __builtin_amdgcn_mfma_f32_32x32x16_bf16(KF(0,0), qf[0], z16, 0, 0, 0);
        f32x16 st1 = __builtin_amdgcn_mfma_f32_32x32x16_bf16(KF(1,0), qf[0], z16, 0, 0, 0);
        #pragma unroll
        for (int kk = 1; kk < 4; kk++) {
            st0 = __builtin_amdgcn_mfma_f32_32x32x16_bf16(KF(0,kk), qf[kk], st0, 0, 0, 0);
            st1 = __builtin_amdgcn_mfma_f32_32x32x16_bf16(KF(1,kk), qf[kk], st1, 0, 0, 0);
        }
        __builtin_amdgcn_s_setprio(0);
        #undef KF

        // per 32-key block: exp2 -> pack -> cross-half swap -> PV
        #pragma unroll
        for (int j = 0; j < 2; j++) {
            const f32x16 s = j ? st1 : st0;
            float p[16];
            #pragma unroll
            for (int r = 0; r < 16; r++) p[r] = __builtin_amdgcn_exp2f(s[r]);
            #pragma unroll
            for (int r = 0; r < 16; r += 4)
                li += (p[r] + p[r+1]) + (p[r+2] + p[r+3]);
            // w[m][u] = bf16x2 of keys 32j + 8m + 4hi + 2u + {0,1}, qrow l31
            u32 w[4][2];
            #pragma unroll
            for (int m = 0; m < 4; m++) {
                asm("v_cvt_pk_bf16_f32 %0, %1, %2"
                    : "=v"(w[m][0]) : "v"(p[4*m+0]), "v"(p[4*m+1]));
                asm("v_cvt_pk_bf16_f32 %0, %1, %2"
                    : "=v"(w[m][1]) : "v"(p[4*m+2]), "v"(p[4*m+3]));
            }
            #pragma unroll
            for (int h2 = 0; h2 < 2; h2++) {
                // swap(w[even m], w[odd m]) across lane halves: afterwards
                // frag word order for step sp is {w[2h2][0], w[2h2][1],
                // w[2h2+1][0], w[2h2+1][1]} = keys 16sp + 8hi + {0..7}.
                asm("v_permlane32_swap_b32 %0, %1"
                    : "+v"(w[2*h2][0]), "+v"(w[2*h2+1][0]));
                asm("v_permlane32_swap_b32 %0, %1"
                    : "+v"(w[2*h2][1]), "+v"(w[2*h2+1][1]));
                const int sp = 2*j + h2;               // 16-key PV step
                union { u32 uw[4]; s16x8 v; } pa;
                pa.uw[0] = w[2*h2][0];   pa.uw[1] = w[2*h2][1];
                pa.uw[2] = w[2*h2+1][0]; pa.uw[3] = w[2*h2+1][1];
                __builtin_amdgcn_s_setprio(1);
                #pragma unroll
                for (int j2 = 0; j2 < 2; j2++) {
                    const int pb = (2*sp + hi + 4*j2 + (l31 >> 3)) & 7;
                    s16x8 vb = *(const s16x8*)&Vt[cur][32*j2 + l31][pb * 8];
                    oacc[j2] = __builtin_amdgcn_mfma_f32_32x32x16_bf16(pa.v, vb, oacc[j2], 0, 0, 0);
                }
                __builtin_amdgcn_s_setprio(0);
            }
        }
    }

    // epilogue: lane's li is the partial for qrow l31 over its key-offsets;
    // pair-reduce across halves, then broadcast 1/li to the C-layout rows.
    li += __shfl_xor(li, 32);
    const float inv = 1.f / li;
    #pragma unroll
    for (int r = 0; r < 16; r++) {
        const int qr = (r & 3) + 8 * (r >> 2) + 4 * hi;
        const float iv = __shfl(inv, qr);
        const size_t grow = (size_t)(b * N_ + n0 + 32*wv + qr);
        #pragma unroll
        for (int j2 = 0; j2 < 2; j2++)
            attout[grow * C_ + h * D_ + 32*j2 + l31] = f2bf(oacc[j2][r] * iv);
    }
}

extern "C" void kernel_launch(void* const* d_in, const int* in_sizes, int n_in,
                              void* d_out, int out_size, void* d_ws, size_t ws_size,
                              hipStream_t stream) {
    const float* x      = (const float*)d_in[0];   // (4,2048,768)
    const float* w_qkv  = (const float*)d_in[1];   // (2304,768)
    const float* w_proj = (const float*)d_in[2];   // (768,768)
    const float* b_proj = (const float*)d_in[3];   // (768,)
    float* out = (float*)d_out;

    const int NX   = B_ * N_ * C_;
    const int NWQ  = 3 * C_ * C_;
    const int NWP  = C_ * C_;
    const int NQKV = B_ * N_ * 3 * C_;

    u16* xb   = (u16*)d_ws;
    u16* wqb  = xb + NX;
    u16* wpb  = wqb + NWQ;
    u16* qkvb = wpb + NWP;
    u16* attb = qkvb + NQKV;

    dim3 blk(256);

    // all three fp32->bf16 conversions in one launch
    cvt_all<<<768, blk, 0, stream>>>((const float4*)x, (const float4*)w_qkv,
                                     (const float4*)w_proj,
                                     (ushort4*)xb, (ushort4*)wqb, (ushort4*)wpb);

    const int M = B_ * N_;   // 8192
    // qkv = x @ w_qkv^T (bf16 out; Q block pre-scaled by 0.125*log2e)
    gemm_mfma<128, 2, true, false, true><<<dim3((3*C_)/128, M/128), blk, 0, stream>>>(
        xb, wqb, nullptr, qkvb, M, 3*C_, C_);

    // flash attention (bf16 in/out), static softmax via exp2
    attn_mfma<<<dim3(N_/128, B_ * H_), blk, 0, stream>>>(qkvb, attb);

    // out = attout @ w_proj^T + b_proj (f32 out)
    gemm_mfma<64, 3, false, true, false><<<dim3(C_/128, M/64), blk, 0, stream>>>(
        attb, wpb, b_proj, out, M, C_, C_);
}

// Round 3
// 206.093 us; speedup vs baseline: 1.0612x; 1.0612x over previous
//
#include <hip/hip_runtime.h>
#include <math.h>

#define B_ 4
#define N_ 2048
#define C_ 768
#define H_ 12
#define D_ 64
// softmax exp(s/8) computed as exp2(s * 0.125*log2(e)); folded into Q pre-scale
#define QKSCALE_ 0.18033688011112042f

typedef unsigned short u16;
typedef unsigned int u32;
typedef short s16x8 __attribute__((ext_vector_type(8)));
typedef float f32x4 __attribute__((ext_vector_type(4)));
typedef float f32x16 __attribute__((ext_vector_type(16)));

__device__ __forceinline__ u16 f2bf(float f) {
    union { float f; u32 u; } v; v.f = f;
    u32 r = (v.u + 0x7fffu + ((v.u >> 16) & 1u)) >> 16;
    return (u16)r;
}

// async global->LDS, 16B per lane; LDS dest = wave-uniform base + lane*16
__device__ __forceinline__ void gl_lds16(const u16* g, u16* l) {
    __builtin_amdgcn_global_load_lds(
        (__attribute__((address_space(1))) void*)g,
        (__attribute__((address_space(3))) void*)l, 16, 0, 0);
}

// fused fp32 -> bf16 conversion of x, w_qkv, w_proj in one launch
#define NX4_  (B_ * N_ * C_ / 4)
#define NWQ4_ (3 * C_ * C_ / 4)
#define NWP4_ (C_ * C_ / 4)
__global__ __launch_bounds__(256) void cvt_all(const float4* __restrict__ x,
                                               const float4* __restrict__ wq,
                                               const float4* __restrict__ wp,
                                               ushort4* __restrict__ xb,
                                               ushort4* __restrict__ wqb,
                                               ushort4* __restrict__ wpb)
{
    const int tot = NX4_ + NWQ4_ + NWP4_;
    int i = blockIdx.x * blockDim.x + threadIdx.x;
    const int stride = gridDim.x * blockDim.x;
    for (; i < tot; i += stride) {
        const float4* s; ushort4* d; int j;
        if (i < NX4_)              { s = x;  d = xb;  j = i; }
        else if (i < NX4_ + NWQ4_) { s = wq; d = wqb; j = i - NX4_; }
        else                       { s = wp; d = wpb; j = i - NX4_ - NWQ4_; }
        float4 v = s[j];
        ushort4 o;
        o.x = f2bf(v.x); o.y = f2bf(v.y); o.z = f2bf(v.z); o.w = f2bf(v.w);
        d[j] = o;
    }
}

// C(M,N) = A(M,K) * B(N,K)^T [+bias]. BMx128 tile, BK=64 (2 MFMA K-steps per
// barrier), double-buffered global_load_lds staging.
// LDS rows of 64 u16 (128B) with 16B-chunk XOR swizzle chunk' = chunk^(row&7).
template<int BM, int WPEU, bool OUT_BF16, bool BIAS, bool QSCALE>
__global__ __launch_bounds__(256, WPEU) void gemm_mfma(const u16* __restrict__ A,
                                                       const u16* __restrict__ Bm,
                                                       const float* __restrict__ bias,
                                                       void* __restrict__ Cout,
                                                       int M, int N, int K)
{
    constexpr int MF  = BM / 32;           // m-frags per wave
    constexpr int AC  = BM / 32;           // A gl_lds calls per wave (8 rows each)
    constexpr int ASZ = BM * 64, BSZ = 128 * 64;
    __shared__ __align__(16) u16 As[2 * ASZ];
    __shared__ __align__(16) u16 Bs[2 * BSZ];
    const int tid  = threadIdx.x;
    const int wv   = tid >> 6;
    const int lane = tid & 63;
    const int lr   = lane & 15;
    const int lq   = lane >> 4;
    const int wm   = (wv >> 1) * (BM / 2);
    const int wn   = (wv & 1) * 64;
    const int row0 = blockIdx.y * BM, col0 = blockIdx.x * 128;

    f32x4 acc[MF][4];
    #pragma unroll
    for (int i = 0; i < MF; i++)
        #pragma unroll
        for (int j = 0; j < 4; j++) { f32x4 z = {0.f,0.f,0.f,0.f}; acc[i][j] = z; }

    const int srow   = lane >> 3;                    // 0..7
    const int schunk = ((lane & 7) ^ srow) * 8;      // swizzled global chunk (u16)

    const int arow_base = (BM / 4) * wv;             // wave's A rows
    const u16* gA = A + (size_t)(row0 + arow_base + srow) * K + schunk;
    const u16* gB = Bm + (size_t)(col0 + 32 * wv + srow) * K + schunk;
    const int aoff = arow_base * 64;
    const int boff = (32 * wv) * 64;

    const int nIter = K / 64;

    // prologue: issue tile 0 into buffer 0
    #pragma unroll
    for (int c = 0; c < AC; c++)
        gl_lds16(gA + (size_t)(8 * c) * K, As + aoff + c * 8 * 64);
    #pragma unroll
    for (int c = 0; c < 4; c++)
        gl_lds16(gB + (size_t)(8 * c) * K, Bs + boff + c * 8 * 64);

    for (int t = 0; t < nIter; t++) {
        const int cur = t & 1;
        __syncthreads();   // buf[cur] staged; buf[cur^1] free
        if (t + 1 < nIter) {
            const int k1 = (t + 1) * 64;
            const int nb = cur ^ 1;
            #pragma unroll
            for (int c = 0; c < AC; c++)
                gl_lds16(gA + (size_t)(8 * c) * K + k1, As + nb * ASZ + aoff + c * 8 * 64);
            #pragma unroll
            for (int c = 0; c < 4; c++)
                gl_lds16(gB + (size_t)(8 * c) * K + k1, Bs + nb * BSZ + boff + c * 8 * 64);
        }
        const u16* __restrict__ Ac = As + cur * ASZ;
        const u16* __restrict__ Bc = Bs + cur * BSZ;
        #pragma unroll
        for (int kk = 0; kk < 2; kk++) {
            const int fo = ((4 * kk + lq) ^ (lr & 7)) * 8;   // swizzled frag pos
            s16x8 af[MF], bfr[4];
            #pragma unroll
            for (int i = 0; i < MF; i++)
                af[i] = *(const s16x8*)&Ac[(wm + 16*i + lr) * 64 + fo];
            #pragma unroll
            for (int j = 0; j < 4; j++)
                bfr[j] = *(const s16x8*)&Bc[(wn + 16*j + lr) * 64 + fo];
            #pragma unroll
            for (int i = 0; i < MF; i++)
                #pragma unroll
                for (int j = 0; j < 4; j++)
                    acc[i][j] = __builtin_amdgcn_mfma_f32_16x16x32_bf16(af[i], bfr[j], acc[i][j], 0, 0, 0);
        }
    }

    #pragma unroll
    for (int i = 0; i < MF; i++) {
        #pragma unroll
        for (int j = 0; j < 4; j++) {
            const int col = col0 + wn + 16*j + lr;
            float bv = BIAS ? bias[col] : 0.f;
            #pragma unroll
            for (int r = 0; r < 4; r++) {
                const int row = row0 + wm + 16*i + lq*4 + r;
                float v = acc[i][j][r] + bv;
                if (QSCALE && col < C_) v *= QKSCALE_;
                if (OUT_BF16) ((u16*)Cout)[(size_t)row * N + col] = f2bf(v);
                else          ((float*)Cout)[(size_t)row * N + col] = v;
            }
        }
    }
}

// MFMA flash attention, 32x32x16 MFMAs, fully in-register softmax (T12).
// R3 vs R2: setprio REMOVED (lockstep 4-wave barrier loop is exactly the
// regime where T5 is null-to-negative per m190; and the tight toggles act as
// compiler scheduling fences around the 2-MFMA PV groups, blocking ds_read/
// MFMA interleave). Kept from R2:
//  * K staging via direct global_load_lds DMA, XOR swizzle applied to the
//    per-lane GLOBAL source address (G21/m173) — LDS contents identical to
//    the reg-staged version, read side unchanged.
//  * XCD-aware block swizzle: all 16 q-tiles of one (b,h) on one XCD ->
//    K/V L2-resident (FETCH_SIZE 104.5 -> 18.5 MB, verified R2).
__global__ __launch_bounds__(256, 3) void attn_mfma(const u16* __restrict__ qkv,
                                                    u16* __restrict__ attout)
{
    __shared__ __align__(16) u16 Ks[2][64 * 64];   // [key][16B-chunk ^ (key&7)]
    __shared__ __align__(16) u16 Vt[2][64][72];    // [d][key], 8-key chunks rotated by d>>3

    const int tid  = threadIdx.x;
    const int wv   = tid >> 6;
    const int lane = tid & 63;
    const int l31  = lane & 31;
    const int hi   = lane >> 5;

    // XCD swizzle: wgid%8 = XCD (round-robin dispatch); give each XCD 6 whole
    // (b,h) groups so K/V is L2-resident per-XCD.
    const int wgid = blockIdx.y * gridDim.x + blockIdx.x;   // 0..767
    const int ix   = wgid >> 3;                             // 0..95 within XCD
    const int bh   = (wgid & 7) * 6 + (ix >> 4);            // 6 bh per XCD
    const int n0   = (ix & 15) * 128;                       // q-tile
    const int b = bh / H_, h = bh % H_;
    const size_t rs = 3 * C_;

    const u16* Qg = qkv + ((size_t)b * N_ + n0) * rs + h * D_;
    const u16* Kg = qkv + ((size_t)b * N_) * rs + C_ + h * D_;
    const u16* Vg = Kg + C_;

    // Q B-frags (32x32x16): lane holds qrow = l31, d = 16*kk + 8*hi + e
    s16x8 qf[4];
    #pragma unroll
    for (int kk = 0; kk < 4; kk++)
        qf[kk] = *(const s16x8*)(Qg + (size_t)(32*wv + l31) * rs + kk*16 + hi*8);

    const f32x16 z16 = {0.f,0.f,0.f,0.f,0.f,0.f,0.f,0.f,
                        0.f,0.f,0.f,0.f,0.f,0.f,0.f,0.f};
    f32x16 oacc[2] = {z16, z16};   // j2: d-blocks 32*j2 + l31
    float li = 0.f;

    // ---- K staging via global_load_lds (2 calls/wave, 8 keys each) ----
    // lane l covers key (l>>3), LDS slot (l&7); slot s of key k must hold
    // global chunk s^(k&7), so per-lane source chunk = (l&7)^((l>>3)&7).
    const int kkey = lane >> 3;                              // 0..7
    const u16* Kg_l = Kg + (size_t)(16*wv + kkey) * rs + ((lane & 7) ^ kkey) * 8;

    // ---- V staging (register transpose-pack) ----
    const int vc = tid & 7, vp = tid >> 3;           // V: 2 keys, 8 d
    const int vkey0 = 2 * vp, vd0 = vc * 8;
    const int vcol0 = (vkey0 + 8 * vc) & 63;

    // prologue: K tile 0 -> DMA into buf0; V tile 0 -> regs -> buf0; V tile 1 -> regs
    gl_lds16(Kg_l,                    &Ks[0][(16*wv) * 64]);
    gl_lds16(Kg_l + (size_t)8 * rs,   &Ks[0][(16*wv + 8) * 64]);

    s16x8 vr0, vr1;
    {
        const u16* vp2 = Vg + (size_t)vkey0 * rs + vd0;
        vr0 = *(const s16x8*)vp2; vr1 = *(const s16x8*)(vp2 + rs);
    }
    #pragma unroll
    for (int u = 0; u < 8; u++) {
        u32 pk = (u32)(u16)vr0[u] | ((u32)(u16)vr1[u] << 16);
        *(u32*)&Vt[0][vd0 + u][vcol0] = pk;
    }
    {
        const u16* vp2 = Vg + (size_t)(64 + vkey0) * rs + vd0;
        vr0 = *(const s16x8*)vp2; vr1 = *(const s16x8*)(vp2 + rs);
    }

    const int NT = N_ / 64;
    for (int t = 0; t < NT; t++) {
        const int cur = t & 1, nxt = cur ^ 1;
        __syncthreads();   // buf[cur] staged (DMA drained); buf[nxt] readers done
        if (t + 1 < NT) {
            // issue next K tile DMA first — full tile of latency to land
            const size_t ko = (size_t)(t + 1) * 64 * rs;
            gl_lds16(Kg_l + ko,                  &Ks[nxt][(16*wv) * 64]);
            gl_lds16(Kg_l + ko + (size_t)8 * rs, &Ks[nxt][(16*wv + 8) * 64]);
            // store reg-prefetched V tile t+1
            #pragma unroll
            for (int u = 0; u < 8; u++) {
                u32 pk = (u32)(u16)vr0[u] | ((u32)(u16)vr1[u] << 16);
                *(u32*)&Vt[nxt][vd0 + u][vcol0] = pk;
            }
        }
        if (t + 2 < NT) {
            const u16* vp2 = Vg + (size_t)((t+2)*64 + vkey0) * rs + vd0;
            vr0 = *(const s16x8*)vp2; vr1 = *(const s16x8*)(vp2 + rs);
        }

        // S^T = K Q^T : two 32-key blocks (j), k = d in 4 chunks of 16 (kk)
        #define KF(j, kk) (*(const s16x8*)&Ks[cur][(32*(j) + l31) * 64 + \
                           ((2*(kk) + hi) ^ (l31 & 7)) * 8])
        f32x16 st0 = __builtin_amdgcn_mfma_f32_32x32x16_bf16(KF(0,0), qf[0], z16, 0, 0, 0);
        f32x16 st1 = __builtin_amdgcn_mfma_f32_32x32x16_bf16(KF(1,0), qf[0], z16, 0, 0, 0);
        #pragma unroll
        for (int kk = 1; kk < 4; kk++) {
            st0 = __builtin_amdgcn_mfma_f32_32x32x16_bf16(KF(0,kk), qf[kk], st0, 0, 0, 0);
            st1 = __builtin_amdgcn_mfma_f32_32x32x16_bf16(KF(1,kk), qf[kk], st1, 0, 0, 0);
        }
        #undef KF

        // per 32-key block: exp2 -> pack -> cross-half swap -> PV
        #pragma unroll
        for (int j = 0; j < 2; j++) {
            const f32x16 s = j ? st1 : st0;
            float p[16];
            #pragma unroll
            for (int r = 0; r < 16; r++) p[r] = __builtin_amdgcn_exp2f(s[r]);
            #pragma unroll
            for (int r = 0; r < 16; r += 4)
                li += (p[r] + p[r+1]) + (p[r+2] + p[r+3]);
            // w[m][u] = bf16x2 of keys 32j + 8m + 4hi + 2u + {0,1}, qrow l31
            u32 w[4][2];
            #pragma unroll
            for (int m = 0; m < 4; m++) {
                asm("v_cvt_pk_bf16_f32 %0, %1, %2"
                    : "=v"(w[m][0]) : "v"(p[4*m+0]), "v"(p[4*m+1]));
                asm("v_cvt_pk_bf16_f32 %0, %1, %2"
                    : "=v"(w[m][1]) : "v"(p[4*m+2]), "v"(p[4*m+3]));
            }
            #pragma unroll
            for (int h2 = 0; h2 < 2; h2++) {
                // swap(w[even m], w[odd m]) across lane halves: afterwards
                // frag word order for step sp is {w[2h2][0], w[2h2][1],
                // w[2h2+1][0], w[2h2+1][1]} = keys 16sp + 8hi + {0..7}.
                asm("v_permlane32_swap_b32 %0, %1"
                    : "+v"(w[2*h2][0]), "+v"(w[2*h2+1][0]));
                asm("v_permlane32_swap_b32 %0, %1"
                    : "+v"(w[2*h2][1]), "+v"(w[2*h2+1][1]));
                const int sp = 2*j + h2;               // 16-key PV step
                union { u32 uw[4]; s16x8 v; } pa;
                pa.uw[0] = w[2*h2][0];   pa.uw[1] = w[2*h2][1];
                pa.uw[2] = w[2*h2+1][0]; pa.uw[3] = w[2*h2+1][1];
                #pragma unroll
                for (int j2 = 0; j2 < 2; j2++) {
                    const int pb = (2*sp + hi + 4*j2 + (l31 >> 3)) & 7;
                    s16x8 vb = *(const s16x8*)&Vt[cur][32*j2 + l31][pb * 8];
                    oacc[j2] = __builtin_amdgcn_mfma_f32_32x32x16_bf16(pa.v, vb, oacc[j2], 0, 0, 0);
                }
            }
        }
    }

    // epilogue: lane's li is the partial for qrow l31 over its key-offsets;
    // pair-reduce across halves, then broadcast 1/li to the C-layout rows.
    li += __shfl_xor(li, 32);
    const float inv = 1.f / li;
    #pragma unroll
    for (int r = 0; r < 16; r++) {
        const int qr = (r & 3) + 8 * (r >> 2) + 4 * hi;
        const float iv = __shfl(inv, qr);
        const size_t grow = (size_t)(b * N_ + n0 + 32*wv + qr);
        #pragma unroll
        for (int j2 = 0; j2 < 2; j2++)
            attout[grow * C_ + h * D_ + 32*j2 + l31] = f2bf(oacc[j2][r] * iv);
    }
}

extern "C" void kernel_launch(void* const* d_in, const int* in_sizes, int n_in,
                              void* d_out, int out_size, void* d_ws, size_t ws_size,
                              hipStream_t stream) {
    const float* x      = (const float*)d_in[0];   // (4,2048,768)
    const float* w_qkv  = (const float*)d_in[1];   // (2304,768)
    const float* w_proj = (const float*)d_in[2];   // (768,768)
    const float* b_proj = (const float*)d_in[3];   // (768,)
    float* out = (float*)d_out;

    const int NX   = B_ * N_ * C_;
    const int NWQ  = 3 * C_ * C_;
    const int NWP  = C_ * C_;
    const int NQKV = B_ * N_ * 3 * C_;

    u16* xb   = (u16*)d_ws;
    u16* wqb  = xb + NX;
    u16* wpb  = wqb + NWQ;
    u16* qkvb = wpb + NWP;
    u16* attb = qkvb + NQKV;

    dim3 blk(256);

    // all three fp32->bf16 conversions in one launch
    cvt_all<<<768, blk, 0, stream>>>((const float4*)x, (const float4*)w_qkv,
                                     (const float4*)w_proj,
                                     (ushort4*)xb, (ushort4*)wqb, (ushort4*)wpb);

    const int M = B_ * N_;   // 8192
    // qkv = x @ w_qkv^T (bf16 out; Q block pre-scaled by 0.125*log2e)
    gemm_mfma<128, 2, true, false, true><<<dim3((3*C_)/128, M/128), blk, 0, stream>>>(
        xb, wqb, nullptr, qkvb, M, 3*C_, C_);

    // flash attention (bf16 in/out), static softmax via exp2
    attn_mfma<<<dim3(N_/128, B_ * H_), blk, 0, stream>>>(qkvb, attb);

    // out = attout @ w_proj^T + b_proj (f32 out)
    gemm_mfma<64, 3, false, true, false><<<dim3(C_/128, M/64), blk, 0, stream>>>(
        attb, wpb, b_proj, out, M, C_, C_);
}